// Round 1
// baseline (518.766 us; speedup 1.0000x reference)
//
#include <hip/hip_runtime.h>
#include <hip/hip_bf16.h>

#define IN_CH 128
#define OUT_CH 128

// ---------------- degree count ----------------
__global__ void count_kernel(const int* __restrict__ col, int* __restrict__ deg, int E) {
    int i = blockIdx.x * blockDim.x + threadIdx.x;
    if (i < E) atomicAdd(&deg[col[i]], 1);
}

// ---------------- dis = rsqrt(deg+1) ----------------
__global__ void dis_kernel(const int* __restrict__ deg, float* __restrict__ dis, int n) {
    int i = blockIdx.x * blockDim.x + threadIdx.x;
    if (i < n) dis[i] = rsqrtf((float)(deg[i] + 1));
}

// ---------------- exclusive scan (3 kernels, 1024 elems/block) ----------------
__global__ void scan_block_kernel(const int* __restrict__ in, int* __restrict__ out,
                                  int* __restrict__ bsums, int n) {
    __shared__ int lds[256];
    int t = threadIdx.x;
    int base = blockIdx.x * 1024;
    int v[4];
    int idx = base + t * 4;
#pragma unroll
    for (int j = 0; j < 4; ++j) v[j] = (idx + j < n) ? in[idx + j] : 0;
    int sum = v[0] + v[1] + v[2] + v[3];
    lds[t] = sum;
    __syncthreads();
    // Hillis-Steele inclusive scan over 256 thread sums
    for (int off = 1; off < 256; off <<= 1) {
        int a = lds[t];
        int bq = (t >= off) ? lds[t - off] : 0;
        __syncthreads();
        lds[t] = a + bq;
        __syncthreads();
    }
    int run = (t == 0) ? 0 : lds[t - 1];
    if (t == 255 && bsums) bsums[blockIdx.x] = lds[255];
#pragma unroll
    for (int j = 0; j < 4; ++j) {
        if (idx + j < n) out[idx + j] = run;
        run += v[j];
    }
}

__global__ void scan_sums_kernel(int* __restrict__ bsums, int nB) {
    __shared__ int lds[256];
    int t = threadIdx.x;
    lds[t] = (t < nB) ? bsums[t] : 0;
    __syncthreads();
    for (int off = 1; off < 256; off <<= 1) {
        int a = lds[t];
        int bq = (t >= off) ? lds[t - off] : 0;
        __syncthreads();
        lds[t] = a + bq;
        __syncthreads();
    }
    if (t < nB) bsums[t] = (t == 0) ? 0 : lds[t - 1];
}

__global__ void scan_add_kernel(int* __restrict__ offs, const int* __restrict__ bsums,
                                int n, int total) {
    int i = blockIdx.x * blockDim.x + threadIdx.x;
    if (i < n) offs[i] += bsums[i >> 10];
    if (i == 0) offs[n] = total;
}

// ---------------- CSR fill (consumes deg via atomicSub) ----------------
__global__ void fill_kernel(const int* __restrict__ row, const int* __restrict__ col,
                            const int* __restrict__ offs, int* __restrict__ deg,
                            int* __restrict__ srcs, int E) {
    int i = blockIdx.x * blockDim.x + threadIdx.x;
    if (i < E) {
        int c = col[i];
        int old = atomicSub(&deg[c], 1);      // old in [1, deg]
        srcs[offs[c] + old - 1] = row[i];
    }
}

// ---------------- aggregation: one wave per node ----------------
__global__ __launch_bounds__(256) void aggregate_kernel(
        const float2* __restrict__ x2, const int* __restrict__ srcs,
        const int* __restrict__ offs, const float* __restrict__ dis,
        float2* __restrict__ out2, int n) {
    int gid = blockIdx.x * blockDim.x + threadIdx.x;
    int wid = gid >> 6;          // wave id = node id
    int lane = gid & 63;
    if (wid >= n) return;
    int beg = offs[wid];
    int end = offs[wid + 1];
    float di = dis[wid];
    float2 xi = x2[(size_t)wid * 64 + lane];
    float accx = di * xi.x;      // self-loop inner term: dis[i] * x[i]
    float accy = di * xi.y;
    for (int e = beg; e < end; ++e) {
        int s = srcs[e];
        float ds = dis[s];
        float2 xs = x2[(size_t)s * 64 + lane];
        accx = fmaf(ds, xs.x, accx);
        accy = fmaf(ds, xs.y, accy);
    }
    float2 r;
    r.x = di * accx;
    r.y = di * accy;
    out2[(size_t)wid * 64 + lane] = r;
}

// ---------------- in-place row GEMM + bias + relu, W in registers ----------------
// 256 threads: thread t -> (channel c = t&127, k-half = t>>7). Each thread holds
// 64 W values in VGPRs. Row broadcast via LDS; halves combined via LDS.
__global__ __launch_bounds__(256) void gemm_kernel(float* __restrict__ io,
                                                   const float* __restrict__ W,
                                                   const float* __restrict__ bias, int n) {
    __shared__ float rowL[128];
    __shared__ float part[128];
    int t = threadIdx.x;
    int c = t & 127;
    int half = t >> 7;           // 0: k in [0,64), 1: k in [64,128)
    float w[64];
#pragma unroll
    for (int j = 0; j < 64; ++j) w[j] = W[(half * 64 + j) * 128 + c];
    float bv = bias[c];
    int kbase = half * 64;
    for (int r = blockIdx.x; r < n; r += gridDim.x) {
        if (t < 128) rowL[t] = io[(size_t)r * 128 + t];
        __syncthreads();
        float acc = 0.f;
#pragma unroll
        for (int j = 0; j < 64; ++j) acc = fmaf(rowL[kbase + j], w[j], acc);
        if (half) part[c] = acc;
        __syncthreads();
        if (!half) {
            float v = acc + part[c] + bv;
            io[(size_t)r * 128 + c] = fmaxf(v, 0.f);
        }
        __syncthreads();   // protect rowL/part before next stage
    }
}

extern "C" void kernel_launch(void* const* d_in, const int* in_sizes, int n_in,
                              void* d_out, int out_size, void* d_ws, size_t ws_size,
                              hipStream_t stream) {
    const float* x  = (const float*)d_in[0];
    const int*   ei = (const int*)d_in[1];
    const float* W  = (const float*)d_in[2];
    const float* b  = (const float*)d_in[3];
    float* out = (float*)d_out;

    int N = in_sizes[0] / IN_CH;
    int E = in_sizes[1] / 2;
    const int* rowp = ei;        // edge_index[0] = source
    const int* colp = ei + E;    // edge_index[1] = target

    // workspace layout (16B aligned chunks)
    char* p = (char*)d_ws;
    auto take = [&](size_t bytes) { char* q = p; p += (bytes + 255) & ~(size_t)255; return q; };
    int*   deg   = (int*)take((size_t)N * 4);
    int*   offs  = (int*)take((size_t)(N + 1) * 4);
    int*   bsums = (int*)take(256 * 4);
    int*   srcs  = (int*)take((size_t)E * 4);
    float* dis   = (float*)take((size_t)N * 4);
    (void)ws_size;

    hipMemsetAsync(deg, 0, (size_t)N * 4, stream);

    int tpb = 256;
    count_kernel<<<(E + tpb - 1) / tpb, tpb, 0, stream>>>(colp, deg, E);
    dis_kernel<<<(N + tpb - 1) / tpb, tpb, 0, stream>>>(deg, dis, N);

    int nB = (N + 1023) / 1024;   // 98 for N=100000 (must be <= 256)
    scan_block_kernel<<<nB, 256, 0, stream>>>(deg, offs, bsums, N);
    scan_sums_kernel<<<1, 256, 0, stream>>>(bsums, nB);
    scan_add_kernel<<<(N + tpb - 1) / tpb, tpb, 0, stream>>>(offs, bsums, N, E);

    fill_kernel<<<(E + tpb - 1) / tpb, tpb, 0, stream>>>(rowp, colp, offs, deg, srcs, E);

    long long threads_agg = (long long)N * 64;
    aggregate_kernel<<<(int)((threads_agg + tpb - 1) / tpb), tpb, 0, stream>>>(
        (const float2*)x, srcs, offs, dis, (float2*)out, N);

    gemm_kernel<<<2048, 256, 0, stream>>>(out, W, b, N);
}

// Round 2
// 432.269 us; speedup vs baseline: 1.2001x; 1.2001x over previous
//
#include <hip/hip_runtime.h>
#include <hip/hip_bf16.h>
#include <hip/hip_fp16.h>

#define IN_CH 128
#define OUT_CH 128
#define TM 64

// ---------------- degree count ----------------
__global__ void count_kernel(const int* __restrict__ col, int* __restrict__ deg, int E) {
    int i = blockIdx.x * blockDim.x + threadIdx.x;
    if (i < E) atomicAdd(&deg[col[i]], 1);
}

// ---------------- exclusive scan block stage (+ fused dis = rsqrt(deg+1)) ----------------
__global__ void scan_block_kernel(const int* __restrict__ in, int* __restrict__ out,
                                  int* __restrict__ bsums, float* __restrict__ dis, int n) {
    __shared__ int lds[256];
    int t = threadIdx.x;
    int base = blockIdx.x * 1024;
    int v[4];
    int idx = base + t * 4;
#pragma unroll
    for (int j = 0; j < 4; ++j) v[j] = (idx + j < n) ? in[idx + j] : 0;
#pragma unroll
    for (int j = 0; j < 4; ++j)
        if (idx + j < n) dis[idx + j] = rsqrtf((float)(v[j] + 1));
    int sum = v[0] + v[1] + v[2] + v[3];
    lds[t] = sum;
    __syncthreads();
    for (int off = 1; off < 256; off <<= 1) {
        int a = lds[t];
        int bq = (t >= off) ? lds[t - off] : 0;
        __syncthreads();
        lds[t] = a + bq;
        __syncthreads();
    }
    int run = (t == 0) ? 0 : lds[t - 1];
    if (t == 255 && bsums) bsums[blockIdx.x] = lds[255];
#pragma unroll
    for (int j = 0; j < 4; ++j) {
        if (idx + j < n) out[idx + j] = run;
        run += v[j];
    }
}

__global__ void scan_sums_kernel(int* __restrict__ bsums, int nB) {
    __shared__ int lds[256];
    int t = threadIdx.x;
    lds[t] = (t < nB) ? bsums[t] : 0;
    __syncthreads();
    for (int off = 1; off < 256; off <<= 1) {
        int a = lds[t];
        int bq = (t >= off) ? lds[t - off] : 0;
        __syncthreads();
        lds[t] = a + bq;
        __syncthreads();
    }
    if (t < nB) bsums[t] = (t == 0) ? 0 : lds[t - 1];
}

__global__ void scan_add_kernel(int* __restrict__ offs, const int* __restrict__ bsums,
                                int n, int total) {
    int i = blockIdx.x * blockDim.x + threadIdx.x;
    if (i < n) offs[i] += bsums[i >> 10];
    if (i == 0) offs[n] = total;
}

// ---------------- CSR fill (consumes deg via atomicSub) ----------------
__global__ void fill_kernel(const int* __restrict__ row, const int* __restrict__ col,
                            const int* __restrict__ offs, int* __restrict__ deg,
                            int* __restrict__ srcs, int E) {
    int i = blockIdx.x * blockDim.x + threadIdx.x;
    if (i < E) {
        int c = col[i];
        int old = atomicSub(&deg[c], 1);
        srcs[offs[c] + old - 1] = row[i];
    }
}

// ---------------- GEMM: h = x @ W, fp32 accumulate, fp16 output ----------------
// block 256 threads, 64 rows/block. W as fp16 in LDS (32KB) + A tile fp32 (32KB).
// Thread tile: 4 rows x 8 ch.
__global__ __launch_bounds__(256) void gemm_h16_kernel(const float* __restrict__ A,
        const float* __restrict__ W, __half* __restrict__ H, int n) {
    __shared__ __half Wh[128 * 128];   // [k][ch], 32 KB
    __shared__ float As[TM * 128];     // 32 KB
    int t = threadIdx.x;
    const float4* W4 = (const float4*)W;
#pragma unroll
    for (int j = 0; j < 16; ++j) {
        int idx = t + 256 * j;         // float4 idx, 4096 total
        float4 v = W4[idx];
        __half2 p0 = __floats2half2_rn(v.x, v.y);
        __half2 p1 = __floats2half2_rn(v.z, v.w);
        *(__half2*)&Wh[idx * 4]     = p0;
        *(__half2*)&Wh[idx * 4 + 2] = p1;
    }
    int row0 = blockIdx.x * TM;
    const float4* A4 = (const float4*)A;
#pragma unroll
    for (int j = 0; j < 8; ++j) {
        int idx = t + 256 * j;          // 0..2047
        int r = idx >> 5;
        int c4 = idx & 31;
        int gr = row0 + r;
        float4 v = make_float4(0.f, 0.f, 0.f, 0.f);
        if (gr < n) v = A4[(size_t)gr * 32 + c4];
        *(float4*)&As[r * 128 + c4 * 4] = v;
    }
    __syncthreads();
    int tcol = t & 15;
    int trow = t >> 4;
    int cb = tcol * 8;
    float acc[4][8];
#pragma unroll
    for (int r = 0; r < 4; ++r)
#pragma unroll
        for (int c = 0; c < 8; ++c) acc[r][c] = 0.f;
    const float* Abase = &As[(trow * 4) * 128];
#pragma unroll 4
    for (int k = 0; k < 128; ++k) {
        float4 wv = *(const float4*)&Wh[k * 128 + cb];   // 8 halves
        const __half2* wh = (const __half2*)&wv;
        float2 w01 = __half22float2(wh[0]);
        float2 w23 = __half22float2(wh[1]);
        float2 w45 = __half22float2(wh[2]);
        float2 w67 = __half22float2(wh[3]);
        float wreg[8] = {w01.x, w01.y, w23.x, w23.y, w45.x, w45.y, w67.x, w67.y};
#pragma unroll
        for (int r = 0; r < 4; ++r) {
            float a = Abase[r * 128 + k];
#pragma unroll
            for (int c = 0; c < 8; ++c) acc[r][c] = fmaf(a, wreg[c], acc[r][c]);
        }
    }
#pragma unroll
    for (int r = 0; r < 4; ++r) {
        int gr = row0 + trow * 4 + r;
        if (gr < n) {
            __half2 o[4];
#pragma unroll
            for (int j = 0; j < 4; ++j) o[j] = __floats2half2_rn(acc[r][2 * j], acc[r][2 * j + 1]);
            *(float4*)&H[(size_t)gr * 128 + cb] = *(float4*)o;
        }
    }
}

// ---------------- aggregation over fp16 h: one wave per node, + bias + relu ------
__global__ __launch_bounds__(256) void aggregate_h16_kernel(
        const __half2* __restrict__ h2, const int* __restrict__ srcs,
        const int* __restrict__ offs, const float* __restrict__ dis,
        const float* __restrict__ bias, float2* __restrict__ out2, int n) {
    int gid = blockIdx.x * blockDim.x + threadIdx.x;
    int wid = gid >> 6;
    int lane = gid & 63;
    if (wid >= n) return;
    int beg = offs[wid];
    int end = offs[wid + 1];
    float di = dis[wid];
    float2 xi = __half22float2(h2[(size_t)wid * 64 + lane]);
    float accx = di * xi.x;
    float accy = di * xi.y;
    int e = beg;
    for (; e + 2 <= end; e += 2) {
        int s0 = srcs[e];
        int s1 = srcs[e + 1];
        float d0 = dis[s0];
        float d1 = dis[s1];
        float2 v0 = __half22float2(h2[(size_t)s0 * 64 + lane]);
        float2 v1 = __half22float2(h2[(size_t)s1 * 64 + lane]);
        accx = fmaf(d0, v0.x, accx);
        accy = fmaf(d0, v0.y, accy);
        accx = fmaf(d1, v1.x, accx);
        accy = fmaf(d1, v1.y, accy);
    }
    if (e < end) {
        int s0 = srcs[e];
        float d0 = dis[s0];
        float2 v0 = __half22float2(h2[(size_t)s0 * 64 + lane]);
        accx = fmaf(d0, v0.x, accx);
        accy = fmaf(d0, v0.y, accy);
    }
    float2 bv = ((const float2*)bias)[lane];
    float2 r;
    r.x = fmaxf(fmaf(di, accx, bv.x), 0.f);
    r.y = fmaxf(fmaf(di, accy, bv.y), 0.f);
    out2[(size_t)wid * 64 + lane] = r;
}

// ================= fallback path (fp32 gather from x, in-place gemm) =============
__global__ __launch_bounds__(256) void aggregate_f32_kernel(
        const float2* __restrict__ x2, const int* __restrict__ srcs,
        const int* __restrict__ offs, const float* __restrict__ dis,
        float2* __restrict__ out2, int n) {
    int gid = blockIdx.x * blockDim.x + threadIdx.x;
    int wid = gid >> 6;
    int lane = gid & 63;
    if (wid >= n) return;
    int beg = offs[wid];
    int end = offs[wid + 1];
    float di = dis[wid];
    float2 xi = x2[(size_t)wid * 64 + lane];
    float accx = di * xi.x;
    float accy = di * xi.y;
    for (int e = beg; e < end; ++e) {
        int s = srcs[e];
        float ds = dis[s];
        float2 xs = x2[(size_t)s * 64 + lane];
        accx = fmaf(ds, xs.x, accx);
        accy = fmaf(ds, xs.y, accy);
    }
    float2 r;
    r.x = di * accx;
    r.y = di * accy;
    out2[(size_t)wid * 64 + lane] = r;
}

__global__ __launch_bounds__(256) void gemm_inplace_kernel(float* __restrict__ io,
                                                           const float* __restrict__ W,
                                                           const float* __restrict__ bias, int n) {
    __shared__ float rowL[128];
    __shared__ float part[128];
    int t = threadIdx.x;
    int c = t & 127;
    int half = t >> 7;
    float w[64];
#pragma unroll
    for (int j = 0; j < 64; ++j) w[j] = W[(half * 64 + j) * 128 + c];
    float bv = bias[c];
    int kbase = half * 64;
    for (int r = blockIdx.x; r < n; r += gridDim.x) {
        if (t < 128) rowL[t] = io[(size_t)r * 128 + t];
        __syncthreads();
        float acc = 0.f;
#pragma unroll
        for (int j = 0; j < 64; ++j) acc = fmaf(rowL[kbase + j], w[j], acc);
        if (half) part[c] = acc;
        __syncthreads();
        if (!half) {
            float v = acc + part[c] + bv;
            io[(size_t)r * 128 + c] = fmaxf(v, 0.f);
        }
        __syncthreads();
    }
}

extern "C" void kernel_launch(void* const* d_in, const int* in_sizes, int n_in,
                              void* d_out, int out_size, void* d_ws, size_t ws_size,
                              hipStream_t stream) {
    const float* x  = (const float*)d_in[0];
    const int*   ei = (const int*)d_in[1];
    const float* W  = (const float*)d_in[2];
    const float* b  = (const float*)d_in[3];
    float* out = (float*)d_out;

    int N = in_sizes[0] / IN_CH;
    int E = in_sizes[1] / 2;
    const int* rowp = ei;        // edge_index[0] = source
    const int* colp = ei + E;    // edge_index[1] = target

    char* p = (char*)d_ws;
    auto take = [&](size_t bytes) { char* q = p; p += (bytes + 255) & ~(size_t)255; return q; };
    int*    deg   = (int*)take((size_t)N * 4);
    int*    offs  = (int*)take((size_t)(N + 1) * 4);
    int*    bsums = (int*)take(256 * 4);
    int*    srcs  = (int*)take((size_t)E * 4);
    float*  dis   = (float*)take((size_t)N * 4);
    __half* h     = (__half*)take((size_t)N * 128 * 2);
    bool fits = ((size_t)(p - (char*)d_ws)) <= ws_size;

    hipMemsetAsync(deg, 0, (size_t)N * 4, stream);

    int tpb = 256;
    count_kernel<<<(E + tpb - 1) / tpb, tpb, 0, stream>>>(colp, deg, E);

    int nB = (N + 1023) / 1024;
    scan_block_kernel<<<nB, 256, 0, stream>>>(deg, offs, bsums, dis, N);
    scan_sums_kernel<<<1, 256, 0, stream>>>(bsums, nB);
    scan_add_kernel<<<(N + tpb - 1) / tpb, tpb, 0, stream>>>(offs, bsums, N, E);

    fill_kernel<<<(E + tpb - 1) / tpb, tpb, 0, stream>>>(rowp, colp, offs, deg, srcs, E);

    long long threads_agg = (long long)N * 64;
    int agg_blocks = (int)((threads_agg + tpb - 1) / tpb);

    if (fits) {
        gemm_h16_kernel<<<(N + TM - 1) / TM, 256, 0, stream>>>(x, W, h, N);
        aggregate_h16_kernel<<<agg_blocks, tpb, 0, stream>>>(
            (const __half2*)h, srcs, offs, dis, b, (float2*)out, N);
    } else {
        aggregate_f32_kernel<<<agg_blocks, tpb, 0, stream>>>(
            (const float2*)x, srcs, offs, dis, (float2*)out, N);
        gemm_inplace_kernel<<<2048, 256, 0, stream>>>(out, W, b, N);
    }
}